// Round 15
// baseline (187.820 us; speedup 1.0000x reference)
//
#include <hip/hip_runtime.h>
#include <math.h>

// ---------------- problem constants ----------------
constexpr int NN1 = 65536;      // level-0 nodes
constexpr int EE  = 1048576;    // edges
constexpr int GG  = 64;         // graphs
constexpr int HH  = 128;        // hidden
constexpr int NPG = 1024;       // nodes/graph level-0
constexpr int EPG = 16384;      // edges/graph
constexpr int K1  = 512;        // keep after pool1 (per graph)
constexpr int M1  = GG * K1;    // 32768
constexpr int K2  = 256;        // keep after pool2
constexpr int M2  = GG * K2;    // 16384

// chunked XCD swizzle: XCD x owns the contiguous chunk [x*n/8, (x+1)*n/8) of work.
__device__ __forceinline__ int xcd_swz(int bid, int nblk)
{
    return (bid & 7) * (nblk >> 3) + (bid >> 3);
}

__device__ __forceinline__ float4 f4add(float4 a, float4 b)
{
    a.x += b.x; a.y += b.y; a.z += b.z; a.w += b.w; return a;
}

// ---------------- GEMM (level 1): C[r] = dinv[r] * (A[r] @ W)  ----------------
// FROZEN. EXACT R5 geometry (measured: VGPR 76, no spill, 47.5us). Re-geometry
// attempts ALL regressed: R6/R7 512thr (126us, VGPR squeeze->spill), R8 256thr 4x8
// (126us), R13 1x8 tile (457us, 4x LDS-floats/FMA -> LDS-throughput-bound).
__global__ __launch_bounds__(256) void gemm1_k(const float* __restrict__ A,
                                               const float* __restrict__ W,
                                               const int* __restrict__ rbeg,
                                               const int* __restrict__ rend,
                                               float* __restrict__ C)
{
    __shared__ float Wl[64 * 160];   // 40960 B
    const int t    = threadIdx.x;
    const int rowg = t >> 3;         // 0..31
    const int cg   = t & 7;          // 0..7
    const int b    = xcd_swz(blockIdx.x, gridDim.x);
    const int r0   = (b << 7) + rowg;

    const float* Ar0 = A + ((size_t)r0 << 7);
    const float* Ar1 = Ar0 + (32 << 7);
    const float* Ar2 = Ar1 + (32 << 7);
    const float* Ar3 = Ar2 + (32 << 7);

    float acc[4][16];
#pragma unroll
    for (int i = 0; i < 4; ++i)
#pragma unroll
        for (int j = 0; j < 16; ++j) acc[i][j] = 0.f;

    // ---- stage chunk 0 ----
    {
        const float4* Wg = (const float4*)W;
#pragma unroll
        for (int i = 0; i < 8; ++i) {
            int idx = t + (i << 8);
            int k   = idx >> 5;
            int c4  = (idx & 31) << 2;
            *(float4*)&Wl[k * 160 + (c4 >> 4) * 20 + (c4 & 15)] = Wg[idx];
        }
    }
    float4 xc0 = *(const float4*)(Ar0), xc1 = *(const float4*)(Ar1);
    float4 xc2 = *(const float4*)(Ar2), xc3 = *(const float4*)(Ar3);
    __syncthreads();

    const float* wbase = &Wl[cg * 20];

#pragma unroll 1
    for (int k0 = 0; k0 < 64; k0 += 4) {
        float4 xn0 = *(const float4*)(Ar0 + k0 + 4);
        float4 xn1 = *(const float4*)(Ar1 + k0 + 4);
        float4 xn2 = *(const float4*)(Ar2 + k0 + 4);
        float4 xn3 = *(const float4*)(Ar3 + k0 + 4);
#pragma unroll
        for (int kk = 0; kk < 4; ++kk) {
            const float* wr = wbase + (k0 + kk) * 160;
            float x0 = ((const float*)&xc0)[kk], x1 = ((const float*)&xc1)[kk];
            float x2 = ((const float*)&xc2)[kk], x3 = ((const float*)&xc3)[kk];
#pragma unroll
            for (int jh = 0; jh < 16; jh += 8) {
                float wv[8];
                *(float4*)&wv[0] = *(const float4*)(wr + jh);
                *(float4*)&wv[4] = *(const float4*)(wr + jh + 4);
#pragma unroll
                for (int j = 0; j < 8; ++j) {
                    acc[0][jh + j] = fmaf(x0, wv[j], acc[0][jh + j]);
                    acc[1][jh + j] = fmaf(x1, wv[j], acc[1][jh + j]);
                    acc[2][jh + j] = fmaf(x2, wv[j], acc[2][jh + j]);
                    acc[3][jh + j] = fmaf(x3, wv[j], acc[3][jh + j]);
                }
            }
        }
        xc0 = xn0; xc1 = xn1; xc2 = xn2; xc3 = xn3;
    }
    __syncthreads();
    // ---- stage chunk 1 ----
    {
        const float4* Wg = (const float4*)(W + 64 * 128);
#pragma unroll
        for (int i = 0; i < 8; ++i) {
            int idx = t + (i << 8);
            int k   = idx >> 5;
            int c4  = (idx & 31) << 2;
            *(float4*)&Wl[k * 160 + (c4 >> 4) * 20 + (c4 & 15)] = Wg[idx];
        }
    }
    __syncthreads();

#pragma unroll 1
    for (int k0 = 64; k0 < 128; k0 += 4) {
        bool pf = (k0 < 124);
        float4 xn0, xn1, xn2, xn3;
        if (pf) {
            xn0 = *(const float4*)(Ar0 + k0 + 4);
            xn1 = *(const float4*)(Ar1 + k0 + 4);
            xn2 = *(const float4*)(Ar2 + k0 + 4);
            xn3 = *(const float4*)(Ar3 + k0 + 4);
        }
#pragma unroll
        for (int kk = 0; kk < 4; ++kk) {
            const float* wr = wbase + (k0 - 64 + kk) * 160;
            float x0 = ((const float*)&xc0)[kk], x1 = ((const float*)&xc1)[kk];
            float x2 = ((const float*)&xc2)[kk], x3 = ((const float*)&xc3)[kk];
#pragma unroll
            for (int jh = 0; jh < 16; jh += 8) {
                float wv[8];
                *(float4*)&wv[0] = *(const float4*)(wr + jh);
                *(float4*)&wv[4] = *(const float4*)(wr + jh + 4);
#pragma unroll
                for (int j = 0; j < 8; ++j) {
                    acc[0][jh + j] = fmaf(x0, wv[j], acc[0][jh + j]);
                    acc[1][jh + j] = fmaf(x1, wv[j], acc[1][jh + j]);
                    acc[2][jh + j] = fmaf(x2, wv[j], acc[2][jh + j]);
                    acc[3][jh + j] = fmaf(x3, wv[j], acc[3][jh + j]);
                }
            }
        }
        if (pf) { xc0 = xn0; xc1 = xn1; xc2 = xn2; xc3 = xn3; }
    }

    // epilogue: scale by dinv[r] = 1/sqrt(deg+1), write
#pragma unroll
    for (int i = 0; i < 4; ++i) {
        int r = r0 + (i << 5);
        float deg = (float)(rend[r] - rbeg[r]) + 1.0f;
        float sc = 1.0f / sqrtf(deg);
        float* cp = C + ((size_t)r << 7) + (cg << 4);
#pragma unroll
        for (int j = 0; j < 16; j += 4) {
            float4 v;
            v.x = acc[i][j] * sc; v.y = acc[i][j + 1] * sc;
            v.z = acc[i][j + 2] * sc; v.w = acc[i][j + 3] * sc;
            *(float4*)(cp + j) = v;
        }
    }
}

// ---------------- GEMM (level 2): C[r] = dinv2[r]*tsel[r] * (A[perm[r]] @ W) ------------
// FROZEN (same body as gemm1_k; row sources via perm, tsel folded into epilogue).
__global__ __launch_bounds__(256) void gemm2_k(const float* __restrict__ A,
                                               const float* __restrict__ W,
                                               const int* __restrict__ rbeg,
                                               const int* __restrict__ rend,
                                               const int* __restrict__ perm,
                                               const float* __restrict__ tsel,
                                               float* __restrict__ C)
{
    __shared__ float Wl[64 * 160];   // 40960 B
    const int t    = threadIdx.x;
    const int rowg = t >> 3;         // 0..31
    const int cg   = t & 7;          // 0..7
    const int b    = xcd_swz(blockIdx.x, gridDim.x);
    const int r0   = (b << 7) + rowg;

    const float* Ar0 = A + ((size_t)perm[r0] << 7);
    const float* Ar1 = A + ((size_t)perm[r0 + 32] << 7);
    const float* Ar2 = A + ((size_t)perm[r0 + 64] << 7);
    const float* Ar3 = A + ((size_t)perm[r0 + 96] << 7);

    float acc[4][16];
#pragma unroll
    for (int i = 0; i < 4; ++i)
#pragma unroll
        for (int j = 0; j < 16; ++j) acc[i][j] = 0.f;

    {
        const float4* Wg = (const float4*)W;
#pragma unroll
        for (int i = 0; i < 8; ++i) {
            int idx = t + (i << 8);
            int k   = idx >> 5;
            int c4  = (idx & 31) << 2;
            *(float4*)&Wl[k * 160 + (c4 >> 4) * 20 + (c4 & 15)] = Wg[idx];
        }
    }
    float4 xc0 = *(const float4*)(Ar0), xc1 = *(const float4*)(Ar1);
    float4 xc2 = *(const float4*)(Ar2), xc3 = *(const float4*)(Ar3);
    __syncthreads();

    const float* wbase = &Wl[cg * 20];

#pragma unroll 1
    for (int k0 = 0; k0 < 64; k0 += 4) {
        float4 xn0 = *(const float4*)(Ar0 + k0 + 4);
        float4 xn1 = *(const float4*)(Ar1 + k0 + 4);
        float4 xn2 = *(const float4*)(Ar2 + k0 + 4);
        float4 xn3 = *(const float4*)(Ar3 + k0 + 4);
#pragma unroll
        for (int kk = 0; kk < 4; ++kk) {
            const float* wr = wbase + (k0 + kk) * 160;
            float x0 = ((const float*)&xc0)[kk], x1 = ((const float*)&xc1)[kk];
            float x2 = ((const float*)&xc2)[kk], x3 = ((const float*)&xc3)[kk];
#pragma unroll
            for (int jh = 0; jh < 16; jh += 8) {
                float wv[8];
                *(float4*)&wv[0] = *(const float4*)(wr + jh);
                *(float4*)&wv[4] = *(const float4*)(wr + jh + 4);
#pragma unroll
                for (int j = 0; j < 8; ++j) {
                    acc[0][jh + j] = fmaf(x0, wv[j], acc[0][jh + j]);
                    acc[1][jh + j] = fmaf(x1, wv[j], acc[1][jh + j]);
                    acc[2][jh + j] = fmaf(x2, wv[j], acc[2][jh + j]);
                    acc[3][jh + j] = fmaf(x3, wv[j], acc[3][jh + j]);
                }
            }
        }
        xc0 = xn0; xc1 = xn1; xc2 = xn2; xc3 = xn3;
    }
    __syncthreads();
    {
        const float4* Wg = (const float4*)(W + 64 * 128);
#pragma unroll
        for (int i = 0; i < 8; ++i) {
            int idx = t + (i << 8);
            int k   = idx >> 5;
            int c4  = (idx & 31) << 2;
            *(float4*)&Wl[k * 160 + (c4 >> 4) * 20 + (c4 & 15)] = Wg[idx];
        }
    }
    __syncthreads();

#pragma unroll 1
    for (int k0 = 64; k0 < 128; k0 += 4) {
        bool pf = (k0 < 124);
        float4 xn0, xn1, xn2, xn3;
        if (pf) {
            xn0 = *(const float4*)(Ar0 + k0 + 4);
            xn1 = *(const float4*)(Ar1 + k0 + 4);
            xn2 = *(const float4*)(Ar2 + k0 + 4);
            xn3 = *(const float4*)(Ar3 + k0 + 4);
        }
#pragma unroll
        for (int kk = 0; kk < 4; ++kk) {
            const float* wr = wbase + (k0 - 64 + kk) * 160;
            float x0 = ((const float*)&xc0)[kk], x1 = ((const float*)&xc1)[kk];
            float x2 = ((const float*)&xc2)[kk], x3 = ((const float*)&xc3)[kk];
#pragma unroll
            for (int jh = 0; jh < 16; jh += 8) {
                float wv[8];
                *(float4*)&wv[0] = *(const float4*)(wr + jh);
                *(float4*)&wv[4] = *(const float4*)(wr + jh + 4);
#pragma unroll
                for (int j = 0; j < 8; ++j) {
                    acc[0][jh + j] = fmaf(x0, wv[j], acc[0][jh + j]);
                    acc[1][jh + j] = fmaf(x1, wv[j], acc[1][jh + j]);
                    acc[2][jh + j] = fmaf(x2, wv[j], acc[2][jh + j]);
                    acc[3][jh + j] = fmaf(x3, wv[j], acc[3][jh + j]);
                }
            }
        }
        if (pf) { xc0 = xn0; xc1 = xn1; xc2 = xn2; xc3 = xn3; }
    }

#pragma unroll
    for (int i = 0; i < 4; ++i) {
        int r = r0 + (i << 5);
        float deg = (float)(rend[r] - rbeg[r]) + 1.0f;
        float sc = tsel[r] / sqrtf(deg);
        float* cp = C + ((size_t)r << 7) + (cg << 4);
#pragma unroll
        for (int j = 0; j < 16; j += 4) {
            float4 v;
            v.x = acc[i][j] * sc; v.y = acc[i][j + 1] * sc;
            v.z = acc[i][j + 2] * sc; v.w = acc[i][j + 3] * sc;
            *(float4*)(cp + j) = v;
        }
    }
}

// ---------------- per-graph CSR build, level 1 (count+scan+fill in one block) ----------
__global__ __launch_bounds__(1024) void build_csr1_k(const int* __restrict__ src, const int* __restrict__ dst,
                                                     int* __restrict__ rbeg, int* __restrict__ rend,
                                                     int* __restrict__ csr)
{
    __shared__ int cnt[NPG];
    int t = threadIdx.x;
    int g = xcd_swz(blockIdx.x, GG);
    int ebase = g * EPG;
    cnt[t] = 0;
    __syncthreads();
#pragma unroll
    for (int k = 0; k < EPG / 1024; ++k) {
        int d = dst[ebase + t + k * 1024] & (NPG - 1);
        atomicAdd(&cnt[d], 1);
    }
    __syncthreads();
    int deg0 = cnt[t];
    int val = deg0;
    for (int off = 1; off < NPG; off <<= 1) {
        int u = (t >= off) ? cnt[t - off] : 0;
        __syncthreads();
        val += u; cnt[t] = val;
        __syncthreads();
    }
    int node = g * NPG + t;
    rbeg[node] = ebase + val - deg0;
    rend[node] = ebase + val;
    cnt[t] = val - deg0;
    __syncthreads();
#pragma unroll
    for (int k = 0; k < EPG / 1024; ++k) {
        int e = ebase + t + k * 1024;
        int d = dst[e] & (NPG - 1);
        int pos = atomicAdd(&cnt[d], 1);
        csr[ebase + pos] = src[e];
    }
}

// ---------------- GCN aggregation over prescaled rows, fused bias+relu+score-projection ----
__global__ __launch_bounds__(256) void agg_feat_k(const float4* __restrict__ XWs,
                                                  const int* __restrict__ rbeg, const int* __restrict__ rend,
                                                  const int* __restrict__ csr,
                                                  const float* __restrict__ bias, const float* __restrict__ Ws,
                                                  float* __restrict__ hout, float* __restrict__ hss, int n)
{
    int b    = xcd_swz(blockIdx.x, gridDim.x);
    int half = threadIdx.x >> 5;
    int lane = threadIdx.x & 31;
    int node = (b << 3) + half;
    if (node >= n) return;
    const float4* Xf = XWs + lane;              // row r at Xf[r*32]

    float4 A = make_float4(0.f, 0.f, 0.f, 0.f), B = A, C = A, D = A;
    int p0 = rbeg[node], p1 = rend[node];
    int p = p0;
    for (; p + 8 <= p1; p += 8) {
        int s0 = csr[p], s1 = csr[p + 1], s2 = csr[p + 2], s3 = csr[p + 3];
        int s4 = csr[p + 4], s5 = csr[p + 5], s6 = csr[p + 6], s7 = csr[p + 7];
        float4 v0 = Xf[(size_t)s0 << 5], v1 = Xf[(size_t)s1 << 5];
        float4 v2 = Xf[(size_t)s2 << 5], v3 = Xf[(size_t)s3 << 5];
        float4 v4 = Xf[(size_t)s4 << 5], v5 = Xf[(size_t)s5 << 5];
        float4 v6 = Xf[(size_t)s6 << 5], v7 = Xf[(size_t)s7 << 5];
        A = f4add(A, v0); B = f4add(B, v1); C = f4add(C, v2); D = f4add(D, v3);
        A = f4add(A, v4); B = f4add(B, v5); C = f4add(C, v6); D = f4add(D, v7);
    }
    for (; p + 4 <= p1; p += 4) {
        int s0 = csr[p], s1 = csr[p + 1], s2 = csr[p + 2], s3 = csr[p + 3];
        float4 v0 = Xf[(size_t)s0 << 5], v1 = Xf[(size_t)s1 << 5];
        float4 v2 = Xf[(size_t)s2 << 5], v3 = Xf[(size_t)s3 << 5];
        A = f4add(A, v0); B = f4add(B, v1); C = f4add(C, v2); D = f4add(D, v3);
    }
    for (; p < p1; ++p) {
        int s = csr[p];
        A = f4add(A, Xf[(size_t)s << 5]);
    }
    float4 acc = f4add(f4add(A, B), f4add(C, D));
    acc = f4add(acc, Xf[(size_t)node << 5]);    // self term (prescaled)

    float dd = 1.0f / sqrtf((float)(p1 - p0) + 1.0f);
    float4 bb = *(const float4*)(bias + (lane << 2));
    acc.x = fmaxf(fmaf(acc.x, dd, bb.x), 0.f);
    acc.y = fmaxf(fmaf(acc.y, dd, bb.y), 0.f);
    acc.z = fmaxf(fmaf(acc.z, dd, bb.z), 0.f);
    acc.w = fmaxf(fmaf(acc.w, dd, bb.w), 0.f);
    *(float4*)(hout + ((size_t)node << 7) + (lane << 2)) = acc;

    float4 wsv = *(const float4*)(Ws + (lane << 2));
    float pq = acc.x * wsv.x + acc.y * wsv.y + acc.z * wsv.z + acc.w * wsv.w;
#pragma unroll
    for (int off = 16; off > 0; off >>= 1) pq += __shfl_down(pq, off, 32);
    if (lane == 0) hss[node] = dd * pq;         // prescaled score
}

// ---- fused score + top-k + (BUILD: lvl-2 CSR, atomic-free) + readout + (HEAD: mlp) ----
// BUILD: each KEPT node iterates its OWN csr1 range (p0/p1 still live in registers
// from the score phase; csr1 slice is L2-hot) -> count, exclusive scan, sequential
// fill. No atomics, no src/dst HBM re-read. csr2 is a separate buffer (no alias).
// HEAD (level 2): block g finishes the whole net: z=x1+x2, relu(z@Wl1+bl1), @Wl2+bl2.
template <int NNE, int KK, bool BUILD, bool HEAD>
__global__ void sctopk_k(const int* __restrict__ rbeg, const int* __restrict__ rend,
                         const int* __restrict__ csr, const float* __restrict__ hss,
                         const float* __restrict__ bsp,
                         int* __restrict__ perm, float* __restrict__ tsel,
                         int* __restrict__ rbeg2, int* __restrict__ rend2,
                         int* __restrict__ csr2,
                         const float* __restrict__ h, float* __restrict__ xout,
                         const float* __restrict__ x1g,
                         const float* __restrict__ Wl1, const float* __restrict__ bl1,
                         const float* __restrict__ Wl2, const float* __restrict__ bl2,
                         float* __restrict__ outp)
{
    __shared__ unsigned long long keys[NNE];
    __shared__ float hl[NNE];
    __shared__ int   pix[KK];
    __shared__ float tsl[KK];
    __shared__ float zm[256];
    __shared__ float red[128];
    int t = threadIdx.x;
    int g = xcd_swz(blockIdx.x, GG);
    int node = g * NNE + t;
    int ebase = g * EPG;
    hl[t] = hss[node];
    __syncthreads();

    // ---- score: gather prescaled neighbor scores from LDS ----
    int p0 = rbeg[node], p1 = rend[node];
    float a = 0.f, b = 0.f, c = 0.f, e = 0.f;
    int p = p0;
    for (; p + 8 <= p1; p += 8) {
        int s0 = csr[p] & (NNE - 1), s1 = csr[p + 1] & (NNE - 1);
        int s2 = csr[p + 2] & (NNE - 1), s3 = csr[p + 3] & (NNE - 1);
        int s4 = csr[p + 4] & (NNE - 1), s5 = csr[p + 5] & (NNE - 1);
        int s6 = csr[p + 6] & (NNE - 1), s7 = csr[p + 7] & (NNE - 1);
        a += hl[s0]; b += hl[s1]; c += hl[s2]; e += hl[s3];
        a += hl[s4]; b += hl[s5]; c += hl[s6]; e += hl[s7];
    }
    for (; p + 4 <= p1; p += 4) {
        int s0 = csr[p] & (NNE - 1), s1 = csr[p + 1] & (NNE - 1);
        int s2 = csr[p + 2] & (NNE - 1), s3 = csr[p + 3] & (NNE - 1);
        a += hl[s0]; b += hl[s1]; c += hl[s2]; e += hl[s3];
    }
    for (; p < p1; ++p) a += hl[csr[p] & (NNE - 1)];
    float dd = 1.0f / sqrtf((float)(p1 - p0) + 1.0f);
    float s = fmaf((a + b) + (c + e) + hl[t], dd, bsp[0]);

    // ---- bitonic sort of (monotone score, NNE-1-idx): exact jax top_k tie-break ----
    unsigned u = __float_as_uint(s);
    u = (u & 0x80000000u) ? ~u : (u | 0x80000000u);
    __syncthreads();
    keys[t] = (((unsigned long long)u) << 32) | (unsigned)(NNE - 1 - t);
    __syncthreads();
    for (int k = 2; k <= NNE; k <<= 1) {
        for (int j = k >> 1; j > 0; j >>= 1) {
            int ixj = t ^ j;
            if (ixj > t) {
                unsigned long long ka = keys[t], kb = keys[ixj];
                bool up = ((t & k) == 0);
                if ((ka > kb) == up) { keys[t] = kb; keys[ixj] = ka; }
            }
            __syncthreads();
        }
    }
    unsigned long long key = keys[NNE - 1 - t];   // rank t
    int idx = NNE - 1 - (int)(key & 0xFFFFFFFFu);
    if (t < KK) {
        unsigned uu = (unsigned)(key >> 32);
        float sc = __uint_as_float((uu & 0x80000000u) ? (uu ^ 0x80000000u) : ~uu);
        float tv = tanhf(sc);
        pix[t] = g * NNE + idx;
        tsl[t] = tv;
        if (BUILD) {                   // level 1: gemm2 consumes these globally
            perm[g * KK + t] = g * NNE + idx;
            tsel[g * KK + t] = tv;
        }
    }

    if (BUILD) {
        __syncthreads();                       // all keys reads done -> regions reusable
        int* nml = (int*)hl;                   // local new-id map (NNE ints)
        int* cnt = (int*)keys;                 // KK counters
        nml[t] = -1;
        __syncthreads();
        if (t < KK) nml[idx] = t;              // local rank of kept node
        __syncthreads();

        // count: own node's kept neighbors (csr1 range, L2-hot; no atomics)
        int myrank = nml[t];
        int deg2 = 0;
        if (myrank >= 0) {
            for (int q = p0; q < p1; ++q)
                if (nml[csr[q] & (NNE - 1)] >= 0) ++deg2;
            cnt[myrank] = deg2;
        }
        __syncthreads();
        // exclusive scan over KK counts
        int deg0 = 0, val = 0;
        if (t < KK) { deg0 = cnt[t]; val = deg0; }
        for (int off = 1; off < KK; off <<= 1) {
            int u2 = (t < KK && t >= off) ? cnt[t - off] : 0;
            __syncthreads();
            if (t < KK) { val += u2; cnt[t] = val; }
            __syncthreads();
        }
        if (t < KK) {
            int n2 = g * KK + t;
            rbeg2[n2] = ebase + val - deg0;
            rend2[n2] = ebase + val;
            cnt[t] = val - deg0;               // start offset
        }
        __syncthreads();
        // fill: sequential per kept node, deterministic, no atomics
        if (myrank >= 0) {
            int pos = ebase + cnt[myrank];
            for (int q = p0; q < p1; ++q) {
                int sl = nml[csr[q] & (NNE - 1)];
                if (sl >= 0) csr2[pos++] = g * KK + sl;
            }
        }
    }

    // ---- readout: x[g] = {col-max | col-mean} over KK kept rows of h*tanh ----
    constexpr int G = NNE / 128;               // row groups
    __syncthreads();                           // keys/cnt last use done
    float* rmax = (float*)keys;                // [G][128]
    float* rsum = rmax + G * 128;              // [G][128]  (2*G*128*4 == 8*NNE bytes)
    int col = t & 127;
    int grp = t >> 7;
    float mx = -INFINITY, sm = 0.f;
#pragma unroll 8
    for (int rr0 = 0; rr0 < KK / G; ++rr0) {
        int rr = grp + rr0 * G;
        int o = pix[rr];
        float tv = tsl[rr];
        float v = h[((size_t)o << 7) + col] * tv;
        mx = fmaxf(mx, v);
        sm += v;
    }
    rmax[grp * 128 + col] = mx;
    rsum[grp * 128 + col] = sm;
    __syncthreads();
    if (!HEAD) {
        if (t < 128) {
            float m = rmax[t], s2 = rsum[t];
#pragma unroll
            for (int j2 = 1; j2 < G; ++j2) {
                m = fmaxf(m, rmax[j2 * 128 + t]);
                s2 += rsum[j2 * 128 + t];
            }
            xout[g * 256 + t] = m;
            xout[g * 256 + 128 + t] = s2 * (1.0f / (float)KK);
        }
    } else {
        // finish the whole net for graph g: z = x1 + x2; relu(z@Wl1+bl1); @Wl2+bl2
        if (t < 128) {
            float m = rmax[t], s2 = rsum[t];
#pragma unroll
            for (int j2 = 1; j2 < G; ++j2) {
                m = fmaxf(m, rmax[j2 * 128 + t]);
                s2 += rsum[j2 * 128 + t];
            }
            zm[t]       = x1g[g * 256 + t]       + m;
            zm[t + 128] = x1g[g * 256 + 128 + t] + s2 * (1.0f / (float)KK);
        }
        __syncthreads();
        if (t < 128) {
            float acc = bl1[t];
            for (int k = 0; k < 256; ++k) acc = fmaf(zm[k], Wl1[k * 128 + t], acc);
            red[t] = fmaxf(acc, 0.f) * Wl2[t];
        }
        __syncthreads();
        for (int off = 64; off > 0; off >>= 1) {
            if (t < off) red[t] += red[t + off];
            __syncthreads();
        }
        if (t == 0) outp[g] = red[0] + bl2[0];
    }
}

// ---------------- launch ----------------
extern "C" void kernel_launch(void* const* d_in, const int* in_sizes, int n_in,
                              void* d_out, int out_size, void* d_ws, size_t ws_size,
                              hipStream_t stream)
{
    const float* x   = (const float*)d_in[0];
    const int*   src = (const int*)d_in[1];
    const int*   dst = (const int*)d_in[2];
    const float* W1  = (const float*)d_in[3];
    const float* b1  = (const float*)d_in[4];
    const float* Ws1 = (const float*)d_in[5];
    const float* bs1 = (const float*)d_in[6];
    const float* W2  = (const float*)d_in[7];
    const float* b2  = (const float*)d_in[8];
    const float* Ws2 = (const float*)d_in[9];
    const float* bs2 = (const float*)d_in[10];
    const float* Wl1 = (const float*)d_in[11];
    const float* bl1 = (const float*)d_in[12];
    const float* Wl2 = (const float*)d_in[13];
    const float* bl2 = (const float*)d_in[14];
    float* out = (float*)d_out;
    char* ws = (char*)d_ws;

    // big regions (time-multiplexed)
    float* XW1 = (float*)(ws);                        // 32MB [0,32M)   (dinv-prescaled)
    float* h1  = (float*)(ws + ((size_t)32 << 20));   // 32MB [32M,64M)
    float* XW2 = (float*)(ws);                        // 16MB [0,16M)   (XW1 dead after agg1)
    float* h2  = (float*)(ws + ((size_t)16 << 20));   // 16MB [16M,32M)
    size_t SB = (size_t)64 << 20;
    auto alloc = [&](size_t bytes) { char* p = ws + SB; SB += (bytes + 255) & ~(size_t)255; return p; };
    int* csr1     = (int*)alloc((size_t)EE * 4);
    int* csr2     = (int*)alloc((size_t)EE * 4);      // separate: BUILD reads csr1 while writing csr2
    int* rbeg1    = (int*)alloc(NN1 * 4);
    int* rend1    = (int*)alloc(NN1 * 4);
    float* hss1   = (float*)alloc(NN1 * 4);
    int* perm1    = (int*)alloc(M1 * 4);
    float* tsel1  = (float*)alloc(M1 * 4);
    int* rbeg2    = (int*)alloc(M1 * 4);
    int* rend2    = (int*)alloc(M1 * 4);
    float* hss2   = (float*)alloc(M1 * 4);
    float* x1b    = (float*)alloc(GG * 256 * 4);
    (void)ws_size; (void)in_sizes; (void)n_in; (void)out_size;

    // ---- level 1 ----
    build_csr1_k<<<GG, 1024, 0, stream>>>(src, dst, rbeg1, rend1, csr1);
    gemm1_k<<<NN1 / 128, 256, 0, stream>>>(x, W1, rbeg1, rend1, XW1);
    agg_feat_k<<<NN1 / 8, 256, 0, stream>>>((const float4*)XW1, rbeg1, rend1, csr1, b1, Ws1, h1, hss1, NN1);
    sctopk_k<NPG, K1, true, false><<<GG, NPG, 0, stream>>>(rbeg1, rend1, csr1, hss1, bs1, perm1, tsel1,
                                                           rbeg2, rend2, csr2, h1, x1b,
                                                           nullptr, nullptr, nullptr, nullptr, nullptr, nullptr);
    // ---- level 2 ----
    gemm2_k<<<M1 / 128, 256, 0, stream>>>(h1, W2, rbeg2, rend2, perm1, tsel1, XW2);
    agg_feat_k<<<M1 / 8, 256, 0, stream>>>((const float4*)XW2, rbeg2, rend2, csr2, b2, Ws2, h2, hss2, M1);
    sctopk_k<K1, K2, false, true><<<GG, K1, 0, stream>>>(rbeg2, rend2, csr2, hss2, bs2, nullptr, nullptr,
                                                         nullptr, nullptr, nullptr, h2, nullptr,
                                                         x1b, Wl1, bl1, Wl2, bl2, out);
}